// Round 1
// baseline (936.981 us; speedup 1.0000x reference)
//
#include <hip/hip_runtime.h>

#define B_ 16
#define C_ 256
#define N_ 2048
#define CK_ 64

using f32x4  = __attribute__((ext_vector_type(4))) float;
using bf16x8 = __attribute__((ext_vector_type(8))) short;
using short4_t = __attribute__((ext_vector_type(4))) short;

static __device__ __forceinline__ float bf2f(short s){
  unsigned u = ((unsigned)(unsigned short)s) << 16;
  float f; __builtin_memcpy(&f, &u, 4); return f;
}
static __device__ __forceinline__ short f2bf(float f){
  unsigned u; __builtin_memcpy(&u, &f, 4);
  unsigned r = (u + 0x7fffu + ((u >> 16) & 1u)) >> 16;   // RNE
  return (short)(unsigned short)r;
}

// ---------------- K0: weights -> bf16 (Wb rows: [0,64)=Wq, [64,128)=Wk, [128,384)=Wv)
__global__ void k_convw(const float* __restrict__ Wq, const float* __restrict__ Wk,
                        const float* __restrict__ Wv, const float* __restrict__ Wl,
                        short* __restrict__ Wb, short* __restrict__ Wlb){
  int i = blockIdx.x*256 + threadIdx.x;
  if(i < 384*C_){
    int o = i >> 8;
    float v;
    if(o < 64)       v = Wq[i];
    else if(o < 128) v = Wk[i - 64*C_];
    else             v = Wv[i - 128*C_];
    Wb[i] = f2bf(v);
  }
  if(i < C_*C_) Wlb[i] = f2bf(Wl[i]);
}

// ---------------- K1: g[b,:] = Wk^T (Wq (sum_n x[b,:,n]))   (exact f32 colsum prep)
__global__ void k_prep_g(const float* __restrict__ x, const float* __restrict__ Wq,
                         const float* __restrict__ Wk, float* __restrict__ g){
  int b = blockIdx.x;
  const float* xb = x + (size_t)b*C_*N_;
  __shared__ float xsum[C_];
  __shared__ float t[CK_];
  int tid = threadIdx.x, w = tid>>6, l = tid&63;
  for(int c = w; c < C_; c += 4){
    const float* row = xb + (size_t)c*N_;
    float s = 0.f;
    for(int n = l; n < N_; n += 64) s += row[n];
    for(int off = 32; off; off >>= 1) s += __shfl_down(s, off);
    if(l == 0) xsum[c] = s;
  }
  __syncthreads();
  if(tid < CK_){
    float s = 0.f;
    const float* wr = Wq + (size_t)tid*C_;
    for(int c = 0; c < C_; ++c) s += wr[c]*xsum[c];
    t[tid] = s;
  }
  __syncthreads();
  float s = 0.f;
  for(int j = 0; j < CK_; ++j) s += Wk[(size_t)j*C_ + tid]*t[j];
  g[b*C_ + tid] = s;
}

// ---------------- K2: inv[b,m] = 1/(1e-9 + dot(g[b,:], x[b,:,m]))
__global__ void k_colsum(const float* __restrict__ x, const float* __restrict__ g,
                         float* __restrict__ inv){
  int b = blockIdx.y;
  int m = blockIdx.x*256 + threadIdx.x;
  __shared__ float gs[C_];
  gs[threadIdx.x] = g[b*C_ + threadIdx.x];
  __syncthreads();
  const float* xb = x + (size_t)b*C_*N_ + m;
  float s = 0.f;
  #pragma unroll 8
  for(int c = 0; c < C_; ++c) s += gs[c]*xb[(size_t)c*N_];
  inv[b*N_ + m] = 1.f/(1e-9f + s);
}

// ---------------- K3: qk[b][n][0..64)=q, [64..128)=k ; vT[b][c'][n] = v*inv (all bf16)
__global__ __launch_bounds__(256,2) void k_qkv(const float* __restrict__ x,
        const short* __restrict__ Wb, const float* __restrict__ inv,
        short* __restrict__ qk, short* __restrict__ vT){
  int b = blockIdx.y; int n0 = blockIdx.x*64;
  int tid = threadIdx.x, w = tid>>6, l = tid&63, lo = l&15, g = l>>4;
  __shared__ short xT[64][40];                 // [n][c-chunk], 80B rows
  const float* xb = x + (size_t)b*C_*N_;
  f32x4 acc[6][4];
  #pragma unroll
  for(int oi=0;oi<6;++oi) for(int nj=0;nj<4;++nj) acc[oi][nj]=(f32x4){0.f,0.f,0.f,0.f};
  for(int cc = 0; cc < C_; cc += 32){
    __syncthreads();
    #pragma unroll
    for(int kk = 0; kk < 4; ++kk){             // stage x^T (pair-packed b32 writes)
      int pp = w + 4*kk;
      int ci = cc + 2*pp;
      float a  = xb[(size_t)ci*N_ + n0 + l];
      float c2 = xb[(size_t)(ci+1)*N_ + n0 + l];
      unsigned pr = (unsigned)(unsigned short)f2bf(a) | (((unsigned)(unsigned short)f2bf(c2))<<16);
      *(unsigned*)(&xT[l][2*pp]) = pr;
    }
    __syncthreads();
    bf16x8 bfr[4];
    #pragma unroll
    for(int nj = 0; nj < 4; ++nj) bfr[nj] = *(const bf16x8*)(&xT[nj*16 + lo][8*g]);
    #pragma unroll
    for(int oi = 0; oi < 6; ++oi){
      int o = w*96 + oi*16 + lo;
      bf16x8 af = *(const bf16x8*)(Wb + (size_t)o*C_ + cc + 8*g);
      #pragma unroll
      for(int nj = 0; nj < 4; ++nj)
        acc[oi][nj] = __builtin_amdgcn_mfma_f32_16x16x32_bf16(af, bfr[nj], acc[oi][nj], 0,0,0);
    }
  }
  #pragma unroll
  for(int oi = 0; oi < 6; ++oi){
    int obase = w*96 + oi*16;
    for(int nj = 0; nj < 4; ++nj){
      int n = n0 + nj*16 + lo;
      if(obase < 128){
        short4_t pk;
        #pragma unroll
        for(int r = 0; r < 4; ++r) pk[r] = f2bf(acc[oi][nj][r]);
        *(short4_t*)(&qk[((size_t)b*N_ + n)*128 + obase + 4*g]) = pk;
      } else {
        float iv = inv[b*N_ + n];
        #pragma unroll
        for(int r = 0; r < 4; ++r){
          int o = obase + 4*g + r;
          vT[((size_t)b*C_ + (o-128))*N_ + n] = f2bf(acc[oi][nj][r]*iv);
        }
      }
    }
  }
}

// ---------------- K4: attention. block=128 rows (4 waves x 32); att[b][n][c'] bf16
__global__ __launch_bounds__(256,2) void k_attn(const short* __restrict__ qk,
                                                const short* __restrict__ vT,
                                                short* __restrict__ att){
  int b = blockIdx.y;
  int n0 = blockIdx.x*128;
  int tid = threadIdx.x;
  int w = tid>>6, l = tid&63, lo = l&15, g = l>>4;

  __shared__ short vt_lds[C_][40];   // [c'][32 m], 80B rows (2-way banks)
  __shared__ short p_lds[4][32][40]; // per-wave p tiles

  const short* qkb = qk + (size_t)b*N_*128;

  bf16x8 qa[2][2];
  #pragma unroll
  for(int rt = 0; rt < 2; ++rt){
    int n = n0 + w*32 + rt*16 + lo;
    const short* qrow = qkb + (size_t)n*128;
    qa[rt][0] = *(const bf16x8*)(qrow + 8*g);
    qa[rt][1] = *(const bf16x8*)(qrow + 32 + 8*g);
  }

  // ---- phase A: per-lane online (max,sumexp); rows = rt*16 + 4g + r
  float pm[8], ps[8];
  #pragma unroll
  for(int i = 0; i < 8; ++i){ pm[i] = -1e30f; ps[i] = 0.f; }
  for(int mt = 0; mt < N_/16; ++mt){
    const short* krow = qkb + (size_t)(mt*16 + lo)*128 + 64;
    bf16x8 kb0 = *(const bf16x8*)(krow + 8*g);
    bf16x8 kb1 = *(const bf16x8*)(krow + 32 + 8*g);
    #pragma unroll
    for(int rt = 0; rt < 2; ++rt){
      f32x4 acc = (f32x4){0.f,0.f,0.f,0.f};
      acc = __builtin_amdgcn_mfma_f32_16x16x32_bf16(qa[rt][0], kb0, acc, 0,0,0);
      acc = __builtin_amdgcn_mfma_f32_16x16x32_bf16(qa[rt][1], kb1, acc, 0,0,0);
      #pragma unroll
      for(int r = 0; r < 4; ++r){
        int i = rt*4 + r;
        float v = acc[r];
        float nm = fmaxf(pm[i], v);
        ps[i] = ps[i]*__expf(pm[i]-nm) + __expf(v-nm);
        pm[i] = nm;
      }
    }
  }
  float rmax[8], rinv[8];
  #pragma unroll
  for(int i = 0; i < 8; ++i){
    float M = pm[i];
    for(int msk = 1; msk < 16; msk <<= 1) M = fmaxf(M, __shfl_xor(M, msk));
    float S = ps[i]*__expf(pm[i]-M);
    for(int msk = 1; msk < 16; msk <<= 1) S += __shfl_xor(S, msk);
    rmax[i] = M; rinv[i] = 1.f/S;
  }

  // ---- phase B: recompute w, p=exp(w-max), PV accumulate
  f32x4 oacc[2][16];
  #pragma unroll
  for(int rt=0;rt<2;++rt) for(int cj=0;cj<16;++cj) oacc[rt][cj]=(f32x4){0.f,0.f,0.f,0.f};
  const short* vtb = vT + (size_t)b*C_*N_;

  for(int mc = 0; mc < N_/32; ++mc){
    int m0 = mc*32;
    __syncthreads();                           // prev-iter PV reads done
    #pragma unroll
    for(int kk = 0; kk < 4; ++kk){             // stage v' chunk [256 c'][32 m]
      int cp = (tid>>2) + 64*kk;
      int ii = tid & 3;
      bf16x8 v8 = *(const bf16x8*)(vtb + (size_t)cp*N_ + m0 + 8*ii);
      *(bf16x8*)(&vt_lds[cp][8*ii]) = v8;
    }
    float pv[2][2][4];
    #pragma unroll
    for(int tau = 0; tau < 2; ++tau){
      const short* krow = qkb + (size_t)(m0 + tau*16 + lo)*128 + 64;
      bf16x8 kb0 = *(const bf16x8*)(krow + 8*g);
      bf16x8 kb1 = *(const bf16x8*)(krow + 32 + 8*g);
      #pragma unroll
      for(int rt = 0; rt < 2; ++rt){
        f32x4 acc = (f32x4){0.f,0.f,0.f,0.f};
        acc = __builtin_amdgcn_mfma_f32_16x16x32_bf16(qa[rt][0], kb0, acc, 0,0,0);
        acc = __builtin_amdgcn_mfma_f32_16x16x32_bf16(qa[rt][1], kb1, acc, 0,0,0);
        #pragma unroll
        for(int r = 0; r < 4; ++r) pv[rt][tau][r] = __expf(acc[r] - rmax[rt*4+r]);
      }
    }
    #pragma unroll
    for(int rt = 0; rt < 2; ++rt)
      #pragma unroll
      for(int tau = 0; tau < 2; ++tau)
        #pragma unroll
        for(int r = 0; r < 4; ++r)
          p_lds[w][rt*16 + 4*g + r][tau*16 + lo] = f2bf(pv[rt][tau][r]);
    __syncthreads();                           // vt + p visible
    bf16x8 pa0 = *(const bf16x8*)(&p_lds[w][lo][8*g]);
    bf16x8 pa1 = *(const bf16x8*)(&p_lds[w][16+lo][8*g]);
    #pragma unroll
    for(int cj = 0; cj < 16; ++cj){
      bf16x8 bv = *(const bf16x8*)(&vt_lds[cj*16 + lo][8*g]);
      oacc[0][cj] = __builtin_amdgcn_mfma_f32_16x16x32_bf16(pa0, bv, oacc[0][cj], 0,0,0);
      oacc[1][cj] = __builtin_amdgcn_mfma_f32_16x16x32_bf16(pa1, bv, oacc[1][cj], 0,0,0);
    }
  }

  short* attb = att + (size_t)b*N_*C_;
  #pragma unroll
  for(int rt = 0; rt < 2; ++rt)
    for(int cj = 0; cj < 16; ++cj)
      #pragma unroll
      for(int r = 0; r < 4; ++r){
        int n = n0 + w*32 + rt*16 + 4*g + r;
        attb[(size_t)n*C_ + cj*16 + lo] = f2bf(oacc[rt][cj][r]*rinv[rt*4+r]);
      }
}

// ---------------- K5: h[b][n][o] = sum_c Wl[o,c]*(x[c,n]-att[n,c]); BN partial sums
__global__ __launch_bounds__(256,2) void k_hgemm(const float* __restrict__ x,
        const short* __restrict__ att, const short* __restrict__ Wlb,
        short* __restrict__ h, float* __restrict__ bnsum, float* __restrict__ bnssq){
  int b = blockIdx.y; int n0 = blockIdx.x*64;
  int tid = threadIdx.x, w = tid>>6, l = tid&63, lo = l&15, g = l>>4;
  __shared__ short rT[64][40];
  const float* xb = x + (size_t)b*C_*N_;
  const short* attb = att + (size_t)b*N_*C_;
  f32x4 acc[4][4];
  #pragma unroll
  for(int ot=0;ot<4;++ot) for(int nj=0;nj<4;++nj) acc[ot][nj]=(f32x4){0.f,0.f,0.f,0.f};
  for(int cc = 0; cc < C_; cc += 32){
    __syncthreads();
    #pragma unroll
    for(int kk = 0; kk < 4; ++kk){
      int pp = w + 4*kk;
      int ci = cc + 2*pp;
      float a  = xb[(size_t)ci*N_ + n0 + l];
      float c2 = xb[(size_t)(ci+1)*N_ + n0 + l];
      unsigned pr = (unsigned)(unsigned short)f2bf(a) | (((unsigned)(unsigned short)f2bf(c2))<<16);
      *(unsigned*)(&rT[l][2*pp]) = pr;
    }
    __syncthreads();
    {   // r = x - att (LDS RMW, b128)
      int n = tid>>2, ii = tid&3;
      bf16x8 av = *(const bf16x8*)(attb + (size_t)(n0+n)*C_ + cc + 8*ii);
      bf16x8* pr = (bf16x8*)(&rT[n][8*ii]);
      bf16x8 xv = *pr, rv;
      #pragma unroll
      for(int j = 0; j < 8; ++j) rv[j] = f2bf(bf2f(xv[j]) - bf2f(av[j]));
      *pr = rv;
    }
    __syncthreads();
    bf16x8 bfr[4];
    #pragma unroll
    for(int nj = 0; nj < 4; ++nj) bfr[nj] = *(const bf16x8*)(&rT[nj*16 + lo][8*g]);
    #pragma unroll
    for(int ot = 0; ot < 4; ++ot){
      int o = w*64 + ot*16 + lo;
      bf16x8 af = *(const bf16x8*)(Wlb + (size_t)o*C_ + cc + 8*g);
      #pragma unroll
      for(int nj = 0; nj < 4; ++nj)
        acc[ot][nj] = __builtin_amdgcn_mfma_f32_16x16x32_bf16(af, bfr[nj], acc[ot][nj], 0,0,0);
    }
  }
  short* hb = h + (size_t)b*N_*C_;
  #pragma unroll
  for(int ot = 0; ot < 4; ++ot)
    for(int nj = 0; nj < 4; ++nj){
      int n = n0 + nj*16 + lo;
      short4_t pk;
      #pragma unroll
      for(int r = 0; r < 4; ++r) pk[r] = f2bf(acc[ot][nj][r]);
      *(short4_t*)(&hb[(size_t)n*C_ + w*64 + ot*16 + 4*g]) = pk;
    }
  #pragma unroll
  for(int ot = 0; ot < 4; ++ot){
    float s4[4] = {0,0,0,0}, q4[4] = {0,0,0,0};
    for(int nj = 0; nj < 4; ++nj)
      #pragma unroll
      for(int r = 0; r < 4; ++r){ float v = acc[ot][nj][r]; s4[r] += v; q4[r] += v*v; }
    #pragma unroll
    for(int r = 0; r < 4; ++r){
      float ss = s4[r], qq = q4[r];
      for(int msk = 1; msk < 16; msk <<= 1){ ss += __shfl_xor(ss, msk); qq += __shfl_xor(qq, msk); }
      if(lo == 0){
        int o = w*64 + ot*16 + 4*g + r;
        atomicAdd(&bnsum[o], ss);
        atomicAdd(&bnssq[o], qq);
      }
    }
  }
}

// ---------------- K6: BN finalize -> scale/shift per channel
__global__ void k_bnfin(const float* __restrict__ bnsum, const float* __restrict__ bnssq,
                        const float* __restrict__ gamma, const float* __restrict__ beta,
                        float* __restrict__ bnsc, float* __restrict__ bnsh){
  int o = threadIdx.x;
  float cnt = (float)(B_*N_);
  float mean = bnsum[o]/cnt;
  float var  = bnssq[o]/cnt - mean*mean;
  float is   = rsqrtf(var + 1e-5f);
  float sc   = gamma[o]*is;
  bnsc[o] = sc;
  bnsh[o] = beta[o] - mean*sc;
}

// ---------------- K7: out[c][n] = x + relu(h*sc+sh)  (LDS transpose of h[n][o])
__global__ void k_final(const float* __restrict__ x, const short* __restrict__ h,
                        const float* __restrict__ bnsc, const float* __restrict__ bnsh,
                        float* __restrict__ out){
  int b = blockIdx.z, c0 = blockIdx.y*64, n0 = blockIdx.x*64;
  int tid = threadIdx.x;
  __shared__ float ht[64][65];
  {
    int n = tid>>2, ii = tid&3;
    #pragma unroll
    for(int p = 0; p < 2; ++p){
      int coff = 32*p + 8*ii;
      bf16x8 hv = *(const bf16x8*)(h + ((size_t)(b*N_ + n0 + n))*C_ + c0 + coff);
      #pragma unroll
      for(int j = 0; j < 8; ++j) ht[n][coff + j] = bf2f(hv[j]);
    }
  }
  __syncthreads();
  int c = tid>>2, i2 = tid&3;
  float sc = bnsc[c0 + c], sh = bnsh[c0 + c];
  const float* xr = x + ((size_t)b*C_ + c0 + c)*N_ + n0 + 16*i2;
  float* orow = out + ((size_t)b*C_ + c0 + c)*N_ + n0 + 16*i2;
  #pragma unroll
  for(int k = 0; k < 16; k += 4){
    f32x4 xv = *(const f32x4*)(xr + k);
    f32x4 ov;
    #pragma unroll
    for(int j = 0; j < 4; ++j){
      float bn = ht[16*i2 + k + j][c]*sc + sh;
      ov[j] = xv[j] + fmaxf(bn, 0.f);
    }
    *(f32x4*)(orow + k) = ov;
  }
}

extern "C" void kernel_launch(void* const* d_in, const int* in_sizes, int n_in,
                              void* d_out, int out_size, void* d_ws, size_t ws_size,
                              hipStream_t stream){
  const float* x     = (const float*)d_in[0];
  const float* Wq    = (const float*)d_in[1];
  const float* Wk    = (const float*)d_in[2];
  const float* Wv    = (const float*)d_in[3];
  const float* Wl    = (const float*)d_in[4];
  const float* gamma = (const float*)d_in[5];
  const float* beta  = (const float*)d_in[6];
  float* out = (float*)d_out;

  char* p = (char*)d_ws;
  float* g    = (float*)p;  p += (size_t)B_*C_*4;
  float* inv  = (float*)p;  p += (size_t)B_*N_*4;
  short* Wb   = (short*)p;  p += (size_t)384*C_*2;
  short* Wlb  = (short*)p;  p += (size_t)C_*C_*2;
  short* qk   = (short*)p;  p += (size_t)B_*N_*128*2;
  short* vT   = (short*)p;  p += (size_t)B_*C_*N_*2;
  short* att  = (short*)p;  p += (size_t)B_*N_*C_*2;
  short* h    = (short*)p;  p += (size_t)B_*N_*C_*2;
  float* bnsum= (float*)p;  p += C_*4;
  float* bnssq= (float*)p;  p += C_*4;
  float* bnsc = (float*)p;  p += C_*4;
  float* bnsh = (float*)p;  p += C_*4;

  hipMemsetAsync(bnsum, 0, 2*C_*sizeof(float), stream);

  k_convw <<<384, 256, 0, stream>>>(Wq, Wk, Wv, Wl, Wb, Wlb);
  k_prep_g<<<B_, 256, 0, stream>>>(x, Wq, Wk, g);
  k_colsum<<<dim3(N_/256, B_), 256, 0, stream>>>(x, g, inv);
  k_qkv   <<<dim3(N_/64, B_), 256, 0, stream>>>(x, Wb, inv, qk, vT);
  k_attn  <<<dim3(N_/128, B_), 256, 0, stream>>>(qk, vT, att);
  k_hgemm <<<dim3(N_/64, B_), 256, 0, stream>>>(x, att, Wlb, h, bnsum, bnssq);
  k_bnfin <<<1, 256, 0, stream>>>(bnsum, bnssq, gamma, beta, bnsc, bnsh);
  k_final <<<dim3(N_/64, C_/64, B_), 256, 0, stream>>>(x, h, bnsc, bnsh, out);
}

// Round 3
// 335.672 us; speedup vs baseline: 2.7914x; 2.7914x over previous
//
#include <hip/hip_runtime.h>

#define B_ 16
#define C_ 256
#define N_ 2048
#define CK_ 64

using f32x4  = __attribute__((ext_vector_type(4))) float;
using bf16x8 = __attribute__((ext_vector_type(8))) short;
using short4_t = __attribute__((ext_vector_type(4))) short;

static __device__ __forceinline__ float bf2f(short s){
  unsigned u = ((unsigned)(unsigned short)s) << 16;
  float f; __builtin_memcpy(&f, &u, 4); return f;
}
static __device__ __forceinline__ short f2bf(float f){
  unsigned u; __builtin_memcpy(&u, &f, 4);
  unsigned r = (u + 0x7fffu + ((u >> 16) & 1u)) >> 16;   // RNE
  return (short)(unsigned short)r;
}

// ---------------- K0: weights -> bf16 (Wb rows: [0,64)=Wq, [64,128)=Wk, [128,384)=Wv)
__global__ void k_convw(const float* __restrict__ Wq, const float* __restrict__ Wk,
                        const float* __restrict__ Wv, const float* __restrict__ Wl,
                        short* __restrict__ Wb, short* __restrict__ Wlb){
  int i = blockIdx.x*256 + threadIdx.x;
  if(i < 384*C_){
    int o = i >> 8;
    float v;
    if(o < 64)       v = Wq[i];
    else if(o < 128) v = Wk[i - 64*C_];
    else             v = Wv[i - 128*C_];
    Wb[i] = f2bf(v);
  }
  if(i < C_*C_) Wlb[i] = f2bf(Wl[i]);
}

// ---------------- K1a: xsum[b,c] = sum_n x[b,c,n]  (f64, wave-per-row, 1024 blocks)
__global__ void k_xsum(const float* __restrict__ x, double* __restrict__ xsum){
  int b = blockIdx.y;
  int c = blockIdx.x*4 + (threadIdx.x>>6);
  int l = threadIdx.x & 63;
  const float* row = x + ((size_t)b*C_ + c)*N_;
  double s = 0.0;
  #pragma unroll
  for(int it = 0; it < 8; ++it){
    f32x4 v = *(const f32x4*)(row + it*256 + l*4);
    s += (double)v[0] + (double)v[1] + (double)v[2] + (double)v[3];
  }
  for(int off = 32; off; off >>= 1) s += __shfl_down(s, off);
  if(l == 0) xsum[b*C_ + c] = s;
}

// ---------------- K1b: g[b,:] = Wk^T (Wq xsum)   (f64 exact colsum prep, tiny)
__global__ void k_prep_g2(const double* __restrict__ xsum, const float* __restrict__ Wq,
                          const float* __restrict__ Wk, double* __restrict__ g){
  int b = blockIdx.x;
  __shared__ double xs[C_];
  __shared__ double t[CK_];
  int tid = threadIdx.x;
  xs[tid] = xsum[b*C_ + tid];
  __syncthreads();
  if(tid < CK_){
    double s = 0.0;
    const float* wr = Wq + (size_t)tid*C_;
    for(int c = 0; c < C_; ++c) s += (double)wr[c]*xs[c];
    t[tid] = s;
  }
  __syncthreads();
  double s = 0.0;
  for(int j = 0; j < CK_; ++j) s += (double)Wk[(size_t)j*C_ + tid]*t[j];
  g[b*C_ + tid] = s;
}

// ---------------- K2: inv[b,m] = 1/(1e-9 + dot(g[b,:], x[b,:,m]))   (f64 accumulate)
__global__ void k_colsum(const float* __restrict__ x, const double* __restrict__ g,
                         float* __restrict__ inv){
  int b = blockIdx.y;
  int m = blockIdx.x*256 + threadIdx.x;
  __shared__ double gs[C_];
  gs[threadIdx.x] = g[b*C_ + threadIdx.x];
  __syncthreads();
  const float* xb = x + (size_t)b*C_*N_ + m;
  double s = 0.0;
  #pragma unroll 4
  for(int c = 0; c < C_; ++c) s += gs[c]*(double)xb[(size_t)c*N_];
  inv[b*N_ + m] = (float)(1.0/(1e-9 + s));
}

// ---------------- K3: qk[b][n][0..64)=q, [64..128)=k ; vT[b][c'][n] = v*inv (all bf16)
__global__ __launch_bounds__(256,2) void k_qkv(const float* __restrict__ x,
        const short* __restrict__ Wb, const float* __restrict__ inv,
        short* __restrict__ qk, short* __restrict__ vT){
  int b = blockIdx.y; int n0 = blockIdx.x*64;
  int tid = threadIdx.x, w = tid>>6, l = tid&63, lo = l&15, g = l>>4;
  __shared__ short xT[64][40];                 // [n][c-chunk], 80B rows
  const float* xb = x + (size_t)b*C_*N_;
  f32x4 acc[6][4];
  #pragma unroll
  for(int oi=0;oi<6;++oi) for(int nj=0;nj<4;++nj) acc[oi][nj]=(f32x4){0.f,0.f,0.f,0.f};
  for(int cc = 0; cc < C_; cc += 32){
    __syncthreads();
    #pragma unroll
    for(int kk = 0; kk < 4; ++kk){             // stage x^T (pair-packed b32 writes)
      int pp = w + 4*kk;
      int ci = cc + 2*pp;
      float a  = xb[(size_t)ci*N_ + n0 + l];
      float c2 = xb[(size_t)(ci+1)*N_ + n0 + l];
      unsigned pr = (unsigned)(unsigned short)f2bf(a) | (((unsigned)(unsigned short)f2bf(c2))<<16);
      *(unsigned*)(&xT[l][2*pp]) = pr;
    }
    __syncthreads();
    bf16x8 bfr[4];
    #pragma unroll
    for(int nj = 0; nj < 4; ++nj) bfr[nj] = *(const bf16x8*)(&xT[nj*16 + lo][8*g]);
    #pragma unroll
    for(int oi = 0; oi < 6; ++oi){
      int o = w*96 + oi*16 + lo;
      bf16x8 af = *(const bf16x8*)(Wb + (size_t)o*C_ + cc + 8*g);
      #pragma unroll
      for(int nj = 0; nj < 4; ++nj)
        acc[oi][nj] = __builtin_amdgcn_mfma_f32_16x16x32_bf16(af, bfr[nj], acc[oi][nj], 0,0,0);
    }
  }
  #pragma unroll
  for(int oi = 0; oi < 6; ++oi){
    int obase = w*96 + oi*16;
    for(int nj = 0; nj < 4; ++nj){
      int n = n0 + nj*16 + lo;
      if(obase < 128){
        short4_t pk;
        #pragma unroll
        for(int r = 0; r < 4; ++r) pk[r] = f2bf(acc[oi][nj][r]);
        *(short4_t*)(&qk[((size_t)b*N_ + n)*128 + obase + 4*g]) = pk;
      } else {
        float iv = inv[b*N_ + n];
        #pragma unroll
        for(int r = 0; r < 4; ++r){
          int o = obase + 4*g + r;
          vT[((size_t)b*C_ + (o-128))*N_ + n] = f2bf(acc[oi][nj][r]*iv);
        }
      }
    }
  }
}

// ---------------- K4: attention. block=128 rows (4 waves x 32); att[b][n][c'] bf16
__global__ __launch_bounds__(256,2) void k_attn(const short* __restrict__ qk,
                                                const short* __restrict__ vT,
                                                short* __restrict__ att){
  int b = blockIdx.y;
  int n0 = blockIdx.x*128;
  int tid = threadIdx.x;
  int w = tid>>6, l = tid&63, lo = l&15, g = l>>4;

  __shared__ short vt_lds[C_][40];   // [c'][32 m], 80B rows (2-way banks)
  __shared__ short p_lds[4][32][40]; // per-wave p tiles

  const short* qkb = qk + (size_t)b*N_*128;

  bf16x8 qa[2][2];
  #pragma unroll
  for(int rt = 0; rt < 2; ++rt){
    int n = n0 + w*32 + rt*16 + lo;
    const short* qrow = qkb + (size_t)n*128;
    qa[rt][0] = *(const bf16x8*)(qrow + 8*g);
    qa[rt][1] = *(const bf16x8*)(qrow + 32 + 8*g);
  }

  // ---- phase A: per-lane online (max,sumexp); rows = rt*16 + 4g + r
  float pm[8], ps[8];
  #pragma unroll
  for(int i = 0; i < 8; ++i){ pm[i] = -1e30f; ps[i] = 0.f; }
  for(int mt = 0; mt < N_/16; ++mt){
    const short* krow = qkb + (size_t)(mt*16 + lo)*128 + 64;
    bf16x8 kb0 = *(const bf16x8*)(krow + 8*g);
    bf16x8 kb1 = *(const bf16x8*)(krow + 32 + 8*g);
    #pragma unroll
    for(int rt = 0; rt < 2; ++rt){
      f32x4 acc = (f32x4){0.f,0.f,0.f,0.f};
      acc = __builtin_amdgcn_mfma_f32_16x16x32_bf16(qa[rt][0], kb0, acc, 0,0,0);
      acc = __builtin_amdgcn_mfma_f32_16x16x32_bf16(qa[rt][1], kb1, acc, 0,0,0);
      #pragma unroll
      for(int r = 0; r < 4; ++r){
        int i = rt*4 + r;
        float v = acc[r];
        float nm = fmaxf(pm[i], v);
        ps[i] = ps[i]*__expf(pm[i]-nm) + __expf(v-nm);
        pm[i] = nm;
      }
    }
  }
  float rmax[8], rinv[8];
  #pragma unroll
  for(int i = 0; i < 8; ++i){
    float M = pm[i];
    for(int msk = 1; msk < 16; msk <<= 1) M = fmaxf(M, __shfl_xor(M, msk));
    float S = ps[i]*__expf(pm[i]-M);
    for(int msk = 1; msk < 16; msk <<= 1) S += __shfl_xor(S, msk);
    rmax[i] = M; rinv[i] = 1.f/S;
  }

  // ---- phase B: recompute w, p=exp(w-max), PV accumulate
  f32x4 oacc[2][16];
  #pragma unroll
  for(int rt=0;rt<2;++rt) for(int cj=0;cj<16;++cj) oacc[rt][cj]=(f32x4){0.f,0.f,0.f,0.f};
  const short* vtb = vT + (size_t)b*C_*N_;

  for(int mc = 0; mc < N_/32; ++mc){
    int m0 = mc*32;
    __syncthreads();                           // prev-iter PV reads done
    #pragma unroll
    for(int kk = 0; kk < 4; ++kk){             // stage v' chunk [256 c'][32 m]
      int cp = (tid>>2) + 64*kk;
      int ii = tid & 3;
      bf16x8 v8 = *(const bf16x8*)(vtb + (size_t)cp*N_ + m0 + 8*ii);
      *(bf16x8*)(&vt_lds[cp][8*ii]) = v8;
    }
    float pv[2][2][4];
    #pragma unroll
    for(int tau = 0; tau < 2; ++tau){
      const short* krow = qkb + (size_t)(m0 + tau*16 + lo)*128 + 64;
      bf16x8 kb0 = *(const bf16x8*)(krow + 8*g);
      bf16x8 kb1 = *(const bf16x8*)(krow + 32 + 8*g);
      #pragma unroll
      for(int rt = 0; rt < 2; ++rt){
        f32x4 acc = (f32x4){0.f,0.f,0.f,0.f};
        acc = __builtin_amdgcn_mfma_f32_16x16x32_bf16(qa[rt][0], kb0, acc, 0,0,0);
        acc = __builtin_amdgcn_mfma_f32_16x16x32_bf16(qa[rt][1], kb1, acc, 0,0,0);
        #pragma unroll
        for(int r = 0; r < 4; ++r) pv[rt][tau][r] = __expf(acc[r] - rmax[rt*4+r]);
      }
    }
    #pragma unroll
    for(int rt = 0; rt < 2; ++rt)
      #pragma unroll
      for(int tau = 0; tau < 2; ++tau)
        #pragma unroll
        for(int r = 0; r < 4; ++r)
          p_lds[w][rt*16 + 4*g + r][tau*16 + lo] = f2bf(pv[rt][tau][r]);
    __syncthreads();                           // vt + p visible
    bf16x8 pa0 = *(const bf16x8*)(&p_lds[w][lo][8*g]);
    bf16x8 pa1 = *(const bf16x8*)(&p_lds[w][16+lo][8*g]);
    #pragma unroll
    for(int cj = 0; cj < 16; ++cj){
      bf16x8 bv = *(const bf16x8*)(&vt_lds[cj*16 + lo][8*g]);
      oacc[0][cj] = __builtin_amdgcn_mfma_f32_16x16x32_bf16(pa0, bv, oacc[0][cj], 0,0,0);
      oacc[1][cj] = __builtin_amdgcn_mfma_f32_16x16x32_bf16(pa1, bv, oacc[1][cj], 0,0,0);
    }
  }

  short* attb = att + (size_t)b*N_*C_;
  #pragma unroll
  for(int rt = 0; rt < 2; ++rt)
    for(int cj = 0; cj < 16; ++cj)
      #pragma unroll
      for(int r = 0; r < 4; ++r){
        int n = n0 + w*32 + rt*16 + 4*g + r;
        attb[(size_t)n*C_ + cj*16 + lo] = f2bf(oacc[rt][cj][r]*rinv[rt*4+r]);
      }
}

// ---------------- K5: h[b][n][o] = sum_c Wl[o,c]*(x[c,n]-att[n,c]); BN partial sums
__global__ __launch_bounds__(256,2) void k_hgemm(const float* __restrict__ x,
        const short* __restrict__ att, const short* __restrict__ Wlb,
        short* __restrict__ h, float* __restrict__ bnsum, float* __restrict__ bnssq){
  int b = blockIdx.y; int n0 = blockIdx.x*64;
  int tid = threadIdx.x, w = tid>>6, l = tid&63, lo = l&15, g = l>>4;
  __shared__ short rT[64][40];
  const float* xb = x + (size_t)b*C_*N_;
  const short* attb = att + (size_t)b*N_*C_;
  f32x4 acc[4][4];
  #pragma unroll
  for(int ot=0;ot<4;++ot) for(int nj=0;nj<4;++nj) acc[ot][nj]=(f32x4){0.f,0.f,0.f,0.f};
  for(int cc = 0; cc < C_; cc += 32){
    __syncthreads();
    #pragma unroll
    for(int kk = 0; kk < 4; ++kk){
      int pp = w + 4*kk;
      int ci = cc + 2*pp;
      float a  = xb[(size_t)ci*N_ + n0 + l];
      float c2 = xb[(size_t)(ci+1)*N_ + n0 + l];
      unsigned pr = (unsigned)(unsigned short)f2bf(a) | (((unsigned)(unsigned short)f2bf(c2))<<16);
      *(unsigned*)(&rT[l][2*pp]) = pr;
    }
    __syncthreads();
    {   // r = x - att (LDS RMW, b128)
      int n = tid>>2, ii = tid&3;
      bf16x8 av = *(const bf16x8*)(attb + (size_t)(n0+n)*C_ + cc + 8*ii);
      bf16x8* pr = (bf16x8*)(&rT[n][8*ii]);
      bf16x8 xv = *pr, rv;
      #pragma unroll
      for(int j = 0; j < 8; ++j) rv[j] = f2bf(bf2f(xv[j]) - bf2f(av[j]));
      *pr = rv;
    }
    __syncthreads();
    bf16x8 bfr[4];
    #pragma unroll
    for(int nj = 0; nj < 4; ++nj) bfr[nj] = *(const bf16x8*)(&rT[nj*16 + lo][8*g]);
    #pragma unroll
    for(int ot = 0; ot < 4; ++ot){
      int o = w*64 + ot*16 + lo;
      bf16x8 af = *(const bf16x8*)(Wlb + (size_t)o*C_ + cc + 8*g);
      #pragma unroll
      for(int nj = 0; nj < 4; ++nj)
        acc[ot][nj] = __builtin_amdgcn_mfma_f32_16x16x32_bf16(af, bfr[nj], acc[ot][nj], 0,0,0);
    }
  }
  short* hb = h + (size_t)b*N_*C_;
  #pragma unroll
  for(int ot = 0; ot < 4; ++ot)
    for(int nj = 0; nj < 4; ++nj){
      int n = n0 + nj*16 + lo;
      short4_t pk;
      #pragma unroll
      for(int r = 0; r < 4; ++r) pk[r] = f2bf(acc[ot][nj][r]);
      *(short4_t*)(&hb[(size_t)n*C_ + w*64 + ot*16 + 4*g]) = pk;
    }
  #pragma unroll
  for(int ot = 0; ot < 4; ++ot){
    float s4[4] = {0,0,0,0}, q4[4] = {0,0,0,0};
    for(int nj = 0; nj < 4; ++nj)
      #pragma unroll
      for(int r = 0; r < 4; ++r){ float v = acc[ot][nj][r]; s4[r] += v; q4[r] += v*v; }
    #pragma unroll
    for(int r = 0; r < 4; ++r){
      float ss = s4[r], qq = q4[r];
      for(int msk = 1; msk < 16; msk <<= 1){ ss += __shfl_xor(ss, msk); qq += __shfl_xor(qq, msk); }
      if(lo == 0){
        int o = w*64 + ot*16 + 4*g + r;
        atomicAdd(&bnsum[o], ss);
        atomicAdd(&bnssq[o], qq);
      }
    }
  }
}

// ---------------- K6: BN finalize -> scale/shift per channel
__global__ void k_bnfin(const float* __restrict__ bnsum, const float* __restrict__ bnssq,
                        const float* __restrict__ gamma, const float* __restrict__ beta,
                        float* __restrict__ bnsc, float* __restrict__ bnsh){
  int o = threadIdx.x;
  float cnt = (float)(B_*N_);
  float mean = bnsum[o]/cnt;
  float var  = bnssq[o]/cnt - mean*mean;
  float is   = rsqrtf(var + 1e-5f);
  float sc   = gamma[o]*is;
  bnsc[o] = sc;
  bnsh[o] = beta[o] - mean*sc;
}

// ---------------- K7: out[c][n] = x + relu(h*sc+sh)  (LDS transpose of h[n][o])
__global__ void k_final(const float* __restrict__ x, const short* __restrict__ h,
                        const float* __restrict__ bnsc, const float* __restrict__ bnsh,
                        float* __restrict__ out){
  int b = blockIdx.z, c0 = blockIdx.y*64, n0 = blockIdx.x*64;
  int tid = threadIdx.x;
  __shared__ float ht[64][65];
  {
    int n = tid>>2, ii = tid&3;
    #pragma unroll
    for(int p = 0; p < 2; ++p){
      int coff = 32*p + 8*ii;
      bf16x8 hv = *(const bf16x8*)(h + ((size_t)(b*N_ + n0 + n))*C_ + c0 + coff);
      #pragma unroll
      for(int j = 0; j < 8; ++j) ht[n][coff + j] = bf2f(hv[j]);
    }
  }
  __syncthreads();
  int c = tid>>2, i2 = tid&3;
  float sc = bnsc[c0 + c], sh = bnsh[c0 + c];
  const float* xr = x + ((size_t)b*C_ + c0 + c)*N_ + n0 + 16*i2;
  float* orow = out + ((size_t)b*C_ + c0 + c)*N_ + n0 + 16*i2;
  #pragma unroll
  for(int k = 0; k < 16; k += 4){
    f32x4 xv = *(const f32x4*)(xr + k);
    f32x4 ov;
    #pragma unroll
    for(int j = 0; j < 4; ++j){
      float bn = ht[16*i2 + k + j][c]*sc + sh;
      ov[j] = xv[j] + fmaxf(bn, 0.f);
    }
    *(f32x4*)(orow + k) = ov;
  }
}

extern "C" void kernel_launch(void* const* d_in, const int* in_sizes, int n_in,
                              void* d_out, int out_size, void* d_ws, size_t ws_size,
                              hipStream_t stream){
  const float* x     = (const float*)d_in[0];
  const float* Wq    = (const float*)d_in[1];
  const float* Wk    = (const float*)d_in[2];
  const float* Wv    = (const float*)d_in[3];
  const float* Wl    = (const float*)d_in[4];
  const float* gamma = (const float*)d_in[5];
  const float* beta  = (const float*)d_in[6];
  float* out = (float*)d_out;

  char* p = (char*)d_ws;
  double* g    = (double*)p; p += (size_t)B_*C_*8;
  double* xsum = (double*)p; p += (size_t)B_*C_*8;
  float* inv  = (float*)p;  p += (size_t)B_*N_*4;
  short* Wb   = (short*)p;  p += (size_t)384*C_*2;
  short* Wlb  = (short*)p;  p += (size_t)C_*C_*2;
  short* qk   = (short*)p;  p += (size_t)B_*N_*128*2;
  short* vT   = (short*)p;  p += (size_t)B_*C_*N_*2;
  short* att  = (short*)p;  p += (size_t)B_*N_*C_*2;
  short* h    = (short*)p;  p += (size_t)B_*N_*C_*2;
  float* bnsum= (float*)p;  p += C_*4;
  float* bnssq= (float*)p;  p += C_*4;
  float* bnsc = (float*)p;  p += C_*4;
  float* bnsh = (float*)p;  p += C_*4;

  hipMemsetAsync(bnsum, 0, 2*C_*sizeof(float), stream);

  k_convw  <<<384, 256, 0, stream>>>(Wq, Wk, Wv, Wl, Wb, Wlb);
  k_xsum   <<<dim3(C_/4, B_), 256, 0, stream>>>(x, xsum);
  k_prep_g2<<<B_, 256, 0, stream>>>(xsum, Wq, Wk, g);
  k_colsum <<<dim3(N_/256, B_), 256, 0, stream>>>(x, g, inv);
  k_qkv    <<<dim3(N_/64, B_), 256, 0, stream>>>(x, Wb, inv, qk, vT);
  k_attn   <<<dim3(N_/128, B_), 256, 0, stream>>>(qk, vT, att);
  k_hgemm  <<<dim3(N_/64, B_), 256, 0, stream>>>(x, att, Wlb, h, bnsum, bnssq);
  k_bnfin  <<<1, 256, 0, stream>>>(bnsum, bnssq, gamma, beta, bnsc, bnsh);
  k_final  <<<dim3(N_/64, C_/64, B_), 256, 0, stream>>>(x, h, bnsc, bnsh, out);
}